// Round 5
// baseline (921.910 us; speedup 1.0000x reference)
//
#include <hip/hip_runtime.h>
#include <hip/hip_bf16.h>

#define DIM 256
#define SEQ 256
#define NB 4096
#define OUT_STRIDE 3073

typedef float f32x4 __attribute__((ext_vector_type(4)));
typedef __bf16 bf16x8 __attribute__((ext_vector_type(8)));
typedef unsigned short u16;
typedef unsigned int u32;

__device__ __forceinline__ float bf2f(u16 h){ return __uint_as_float(((u32)h)<<16); }
__device__ __forceinline__ u16 f2bf(float f){
  u32 u = __float_as_uint(f);
  return (u16)((u + 0x7FFFu + ((u>>16)&1u)) >> 16);
}
__device__ __forceinline__ float gelu_f(float x){
  float u = 0.7978845608028654f*(x + 0.044715f*x*x*x);
  float e = __expf(2.0f*u);
  float t = 1.0f - 2.0f/(e+1.0f);
  return 0.5f*x*(1.0f+t);
}
// soft barrier: sync LDS only; leave global loads/stores in flight (T4)
__device__ __forceinline__ void soft_bar(){
  asm volatile("s_waitcnt lgkmcnt(0)" ::: "memory");
  __builtin_amdgcn_s_barrier();
  asm volatile("" ::: "memory");
}

__device__ const int d_nsrc[10] = {0,1,2,1,2,2,3,2,3,3};
__device__ const int d_srcs[10][3] = {{0,0,0},{0,0,0},{0,1,0},{1,0,0},{2,3,0},
                                      {2,4,0},{1,3,5},{4,5,0},{5,6,7},{6,7,8}};

// ---------------- table f32 -> bf16 ----------------
__global__ void k_convert_table(const float* __restrict__ src, u16* __restrict__ dst, int n4){
  int i = blockIdx.x*blockDim.x + threadIdx.x;
  if (i >= n4) return;
  float4 v = ((const float4*)src)[i];
  ushort4 o; o.x=f2bf(v.x); o.y=f2bf(v.y); o.z=f2bf(v.z); o.w=f2bf(v.w);
  ((ushort4*)dst)[i] = o;
}

// ---------------- weight pack into MFMA B-fragment layout ----------------
__global__ void k_pack(const float* __restrict__ nw1, const float* __restrict__ nw2,
                       const float* __restrict__ rw,  const float* __restrict__ ww1,
                       const float* __restrict__ ww2, const float* __restrict__ tw1,
                       const float* __restrict__ tw2, const float* __restrict__ cw,
                       const float* __restrict__ sw1, u16* __restrict__ dst){
  int g = blockIdx.x*blockDim.x + threadIdx.x;
  if (g >= 344064) return;
  const float* base; int gpm, K, N, segStart;
  if      (g < 81920) { base=nw1; gpm=8192; K=256; N=256; segStart=0; }
  else if (g < 163840){ base=nw2; gpm=8192; K=256; N=256; segStart=81920; }
  else if (g < 245760){ base=rw;  gpm=8192; K=256; N=256; segStart=163840; }
  else if (g < 278528){ base=ww1; gpm=8192; K=256; N=256; segStart=245760; }
  else if (g < 311296){ base=ww2; gpm=8192; K=256; N=256; segStart=278528; }
  else if (g < 315392){ base=tw1; gpm=4096; K=256; N=128; segStart=311296; }
  else if (g < 319488){ base=tw2; gpm=4096; K=128; N=256; segStart=315392; }
  else if (g < 327680){ base=cw;  gpm=8192; K=256; N=256; segStart=319488; }
  else                { base=sw1; gpm=16384;K=256; N=512; segStart=327680; }
  int gs = g - segStart;
  int mat = gs / gpm, gl = gs % gpm;
  int lane = gl & 63, g2 = gl >> 6;
  int Nt = N >> 4;
  int t = g2 % Nt, kk = g2 / Nt;
  int col = t*16 + (lane & 15);
  int k0  = kk*32 + (lane >> 4)*8;
  const float* m = base + (size_t)mat*K*N;
  u16* o = dst + (size_t)g*8;
  (void)K;
  #pragma unroll
  for (int j=0;j<8;j++) o[j] = f2bf(m[(size_t)(k0+j)*N + col]);
}

// ---------------- embedding gather + mean ----------------
template<typename T>
__global__ void k_embed(const int* __restrict__ x, const T* __restrict__ table, u16* __restrict__ emb){
  __shared__ float red[4][256];
  int b = blockIdx.x;
  int tid = threadIdx.x, w = tid>>6, lane = tid&63;
  const int* xb = x + b*SEQ;
  float a0=0.f,a1=0.f,a2=0.f,a3=0.f;
  #pragma unroll 4
  for (int ii=0; ii<64; ii++){
    int idx = xb[w*64+ii];
    if constexpr (sizeof(T)==2){
      ushort4 v = *(const ushort4*)(table + (size_t)idx*DIM + lane*4);
      a0+=bf2f(v.x); a1+=bf2f(v.y); a2+=bf2f(v.z); a3+=bf2f(v.w);
    } else {
      float4 v = *(const float4*)(table + (size_t)idx*DIM + lane*4);
      a0+=v.x; a1+=v.y; a2+=v.z; a3+=v.w;
    }
  }
  red[w][lane*4+0]=a0; red[w][lane*4+1]=a1; red[w][lane*4+2]=a2; red[w][lane*4+3]=a3;
  __syncthreads();
  float s = (red[0][tid]+red[1][tid]+red[2][tid]+red[3][tid]) * (1.0f/SEQ);
  emb[(size_t)b*DIM + tid] = f2bf(s);
}

// ---------------- main fused network ----------------
__device__ __forceinline__ bf16x8 lds_readA(const u16* base, int rs, int kk, int lane){
  int row = lane & 15;
  int kbyte = kk*64 + (lane>>4)*16;
  return *(const bf16x8*)((const char*)base + row*rs + (kbyte ^ ((row&7)<<4)));
}

template<int KS>
__device__ __forceinline__ void loadB(bf16x8* dst, const bf16x8* __restrict__ w,
                                      int idx0, int nt, int lane){
  #pragma unroll
  for (int kk=0;kk<KS;kk++) dst[kk] = w[((size_t)(kk*nt+idx0))*64 + lane];
}
template<int KS>
__device__ __forceinline__ void mfmaK(const u16* A, int rs, const bf16x8* b, f32x4& acc, int lane){
  #pragma unroll
  for (int kk=0;kk<KS;kk++){
    bf16x8 a = lds_readA(A, rs, kk, lane);
    acc = __builtin_amdgcn_mfma_f32_16x16x32_bf16(a, b[kk], acc, 0, 0, 0);
  }
}

__device__ __forceinline__ f32x4 acc_make(float bv){
  f32x4 t = {bv,bv,bv,bv};
  return t;
}

template<bool GELU>
__device__ __forceinline__ void epi1(f32x4 acc, u16* dst, int rs, int colbase, int lane,
                                     const float* __restrict__ addcol){
  int col = colbase + (lane&15);
  float add = addcol ? addcol[col] : 0.0f;
  #pragma unroll
  for (int r=0;r<4;r++){
    int row = (lane>>4)*4 + r;
    float v = acc[r];
    if (GELU) v = gelu_f(v);
    v += add;
    *(u16*)((char*)dst + row*rs + ((col*2) ^ ((row&7)<<4))) = f2bf(v);
  }
}

// 16 waves: wave w handles row w; 4 chunks of 64 contiguous floats
__device__ __forceinline__ void out_write(const u16* buf, int rs, float* __restrict__ out,
                                          size_t rowBase, int colBase, int wave, int lane){
  int r = wave;
  int sw = (r&7)<<4;
  #pragma unroll
  for (int cc=0; cc<4; cc++){
    int c = cc*64 + lane;
    float v = bf2f(*(const u16*)((const char*)buf + r*rs + ((c*2)^sw)));
    out[(rowBase + r)*OUT_STRIDE + colBase + c] = v;
  }
}

__global__ __launch_bounds__(1024) __attribute__((amdgpu_waves_per_eu(4,4)))
void k_main(
  const u16* __restrict__ wfrag, const u16* __restrict__ emb,
  const float* __restrict__ nb1, const float* __restrict__ nb2, const float* __restrict__ rb,
  const float* __restrict__ wb1, const float* __restrict__ wb2,
  const float* __restrict__ tb1, const float* __restrict__ tb2,
  const float* __restrict__ voidv, const float* __restrict__ cb,
  const float* __restrict__ sb1, const float* __restrict__ sb2, const float* __restrict__ sw2,
  const int* __restrict__ niter_p, float* __restrict__ out)
{
  __shared__ u16 states[10][16][256];   // XOR-swizzled, rs=512B
  __shared__ u16 abuf[16][512];         // rs=1024B: [:,0:256]=h1/hidden/created, [:,256:512]=inc
  __shared__ u16 cbuf[16][256];         // rs=512B : cur / contracted+void
  __shared__ u16 hbuf[16][512];         // rs=1024B: shek hidden
  __shared__ float red[16][65];

  const int tid = threadIdx.x, wave = tid>>6, lane = tid&63;
  const int blk = blockIdx.x;
  const int niter = *niter_p;
  const bf16x8* wf = (const bf16x8*)wfrag;
  const int bcol = wave*16 + (lane&15);

  // load embedded -> all 10 states (swizzled). 1024 threads: 4 bf16 (8B) each.
  {
    int r = tid >> 6, c0 = (tid & 63) * 4;
    uint2 v = *(const uint2*)(emb + ((size_t)(blk*16 + r))*DIM + c0);
    int sw = (r&7)<<4;
    #pragma unroll
    for (int st=0; st<10; st++){
      char* bp = (char*)states[st];
      *(uint2*)(bp + r*512 + ((c0*2) ^ sw)) = v;
    }
  }

  // strict 2-buffer weight pipeline (64 VGPRs max live weight state)
  bf16x8 b1[8], b2[8];
  float bn1;
  loadB<8>(b1, (niter>0) ? wf : (wf + 245760), wave, 16, lane);
  bn1 = (niter>0) ? nb1[bcol] : wb1[bcol];
  soft_bar();

  // node step: entry cur=W1_i; exit: oth=W1_{i+1} (or worlds_w1[0])
  auto node_step = [&](int i, bf16x8* cur, bf16x8* oth, bool last){
    int ns = d_nsrc[i];
    // ---- stage A: h1 = gelu(states[i] @ W1_i + b1_i); prefetch W2_i -> oth ----
    loadB<8>(oth, wf + 81920 + (size_t)i*8192, wave, 16, lane);
    float c1 = bn1;
    bn1 = nb2[i*DIM + bcol];
    float rbv = (ns>0) ? rb[i*DIM + bcol] : 0.f;
    f32x4 accA = acc_make(c1);
    mfmaK<8>(&states[i][0][0], 512, cur, accA, lane);
    epi1<true>(accA, &abuf[0][0], 1024, wave*16, lane, nullptr);
    if (ns > 0){
      int r = wave, sw = (r&7)<<4;
      int off = ((lane*8) ^ sw);
      const char* s0 = (const char*)states[d_srcs[i][0]] + r*512;
      const char* s1 = (ns>1) ? ((const char*)states[d_srcs[i][1]] + r*512) : nullptr;
      const char* s2 = (ns>2) ? ((const char*)states[d_srcs[i][2]] + r*512) : nullptr;
      uint2 v0 = *(const uint2*)(s0+off);
      uint2 v1, v2; v1.x=v1.y=0u; v2.x=v2.y=0u;
      if (s1) v1 = *(const uint2*)(s1+off);
      if (s2) v2 = *(const uint2*)(s2+off);
      float ax = __uint_as_float(v0.x<<16) + __uint_as_float(v1.x<<16) + __uint_as_float(v2.x<<16);
      float bx = __uint_as_float(v0.x&0xffff0000u) + __uint_as_float(v1.x&0xffff0000u) + __uint_as_float(v2.x&0xffff0000u);
      float ay = __uint_as_float(v0.y<<16) + __uint_as_float(v1.y<<16) + __uint_as_float(v2.y<<16);
      float by = __uint_as_float(v0.y&0xffff0000u) + __uint_as_float(v1.y&0xffff0000u) + __uint_as_float(v2.y&0xffff0000u);
      uint2 o; o.x = (u32)f2bf(ax) | ((u32)f2bf(bx)<<16);
      o.y = (u32)f2bf(ay) | ((u32)f2bf(by)<<16);
      *(uint2*)((char*)abuf + r*1024 + 512 + off) = o;
    }
    soft_bar();
    // ---- stage B: states[i] = h1@W2 + b2 [+ inc@recvW + recv_b] ----
    if (ns > 0) loadB<8>(cur, wf + 163840 + (size_t)i*8192, wave, 16, lane);  // recvW -> cur
    f32x4 accB = acc_make(bn1 + rbv);
    mfmaK<8>(&abuf[0][0], 1024, oth, accB, lane);          // h1 @ W2 (oth)
    const bf16x8* nW = (i<9) ? (wf + (size_t)(i+1)*8192)
                             : (!last ? wf : (wf + 245760));
    loadB<8>(oth, nW, wave, 16, lane);                      // next W1 -> oth (W2 consumed)
    bn1 = (i<9) ? nb1[(i+1)*DIM + bcol] : (!last ? nb1[bcol] : wb1[bcol]);
    if (ns > 0)
      mfmaK<8>((const u16*)((const char*)&abuf[0][0] + 512), 1024, cur, accB, lane);
    epi1<false>(accB, &states[i][0][0], 512, wave*16, lane, nullptr);
    soft_bar();
    if (last)  // overlap output drain with remaining compute
      out_write(&states[i][0][0], 512, out, (size_t)blk*16, i*256, wave, lane);
  };

  for (int it=0; it<niter; it++){
    bool last = (it == niter-1);
    for (int i=0; i<10; i++){
      if (i & 1) node_step(i, b2, b1, last);
      else       node_step(i, b1, b2, last);
    }
  }
  if (niter == 0){
    #pragma unroll
    for (int st=0; st<10; st++)
      out_write(&states[st][0][0], 512, out, (size_t)blk*16, st*256, wave, lane);
  }

  // ---- worlds (entry: b1 = world_w1[0]; b1 stays cur, b2 stays oth) ----
  for (int w=0; w<4; w++){
    loadB<8>(b2, wf + 278528 + (size_t)w*8192, wave, 16, lane);   // ww2[w]
    float c1 = bn1;
    bn1 = wb2[w*DIM + bcol];
    f32x4 a1 = acc_make(c1);
    mfmaK<8>((w==0) ? &states[9][0][0] : &cbuf[0][0], 512, b1, a1, lane);
    epi1<true>(a1, &abuf[0][0], 1024, wave*16, lane, nullptr);
    soft_bar();
    f32x4 a2 = acc_make(bn1);
    mfmaK<8>(&abuf[0][0], 1024, b2, a2, lane);
    if (w < 3){
      loadB<8>(b1, wf + 245760 + (size_t)(w+1)*8192, wave, 16, lane);
      bn1 = wb1[(w+1)*DIM + bcol];
    } else {
      loadB<8>(b1, wf + 311296, wave, 8, lane);   // tz1 (NT=8); waves>=8 read junk (unused)
      bn1 = tb1[bcol & 127];
    }
    epi1<false>(a2, &cbuf[0][0], 512, wave*16, lane, nullptr);
    soft_bar();
  }
  out_write(&cbuf[0][0], 512, out, (size_t)blk*16, 2560, wave, lane);   // cur

  // ---- tz1: hidden = gelu(cur @ tz_w1 + tb1), N=128 (waves 0-7); prefetch tz2 -> b2 ----
  loadB<4>(b2, wf + 315392, wave, 16, lane);   // tz2 (KS=4)
  {
    float c1 = bn1;
    bn1 = tb2[bcol];
    if (wave < 8){
      f32x4 a = acc_make(c1);
      mfmaK<8>(&cbuf[0][0], 512, b1, a, lane);
      epi1<true>(a, &abuf[0][0], 1024, wave*16, lane, nullptr);
    }
  }
  soft_bar();
  // ---- tz2: ctv = (hidden @ tz_w2 + tb2) + void -> cbuf; prefetch cre -> b1 ----
  loadB<8>(b1, wf + 319488, wave, 16, lane);
  {
    float c1 = bn1;
    bn1 = cb[bcol];
    f32x4 a = acc_make(c1);
    mfmaK<4>(&abuf[0][0], 1024, b2, a, lane);
    epi1<false>(a, &cbuf[0][0], 512, wave*16, lane, voidv);
  }
  soft_bar();
  // ---- cre: created = ctv @ cre_w + cre_b -> abuf; prefetch shek halves -> b2, b1 ----
  loadB<8>(b2, wf + 327680, wave*2, 32, lane);
  float bnS0, bnS1;
  {
    float c1 = bn1;
    bnS0 = sb1[wave*32 + (lane&15)];
    bnS1 = sb1[wave*32 + 16 + (lane&15)];
    f32x4 a = acc_make(c1);
    mfmaK<8>(&cbuf[0][0], 512, b1, a, lane);
    loadB<8>(b1, wf + 327680, wave*2+1, 32, lane);   // shek half1 (cre weights consumed)
    epi1<false>(a, &abuf[0][0], 1024, wave*16, lane, nullptr);
  }
  soft_bar();
  // ---- shek1: h = gelu(created @ shek_w1 + sb1), N=512 -> hbuf ----
  {
    f32x4 a0 = acc_make(bnS0);
    f32x4 a1 = acc_make(bnS1);
    mfmaK<8>(&abuf[0][0], 1024, b2, a0, lane);
    mfmaK<8>(&abuf[0][0], 1024, b1, a1, lane);
    epi1<true>(a0, &hbuf[0][0], 1024, (wave*2+0)*16, lane, nullptr);
    epi1<true>(a1, &hbuf[0][0], 1024, (wave*2+1)*16, lane, nullptr);
  }
  soft_bar();
  // ---- shek2: sigmoid(h @ sw2 + sb2) -> out[:,3072] ----
  {
    int r = tid>>6, p = tid&63;
    int sw = (r&7)<<4;
    float partial = 0.f;
    #pragma unroll
    for (int j=0;j<8;j++){
      int k = p*8+j;
      partial += bf2f(*(const u16*)((const char*)hbuf + r*1024 + ((k*2)^sw))) * sw2[k];
    }
    red[r][p] = partial;
    soft_bar();
    if (tid < 16){
      float s = sb2[0];
      #pragma unroll
      for (int p2=0;p2<64;p2++) s += red[tid][p2];
      out[((size_t)(blk*16+tid))*OUT_STRIDE + 3072] = 1.f/(1.f+__expf(-s));
    }
  }
  // created -> out[:,2816:3072]  (states already written during last iteration)
  out_write(&abuf[0][0], 1024, out, (size_t)blk*16, 2816, wave, lane);
}

extern "C" void kernel_launch(void* const* d_in, const int* in_sizes, int n_in,
                              void* d_out, int out_size, void* d_ws, size_t ws_size,
                              hipStream_t stream){
  const int*   x     = (const int*)d_in[0];
  const int*   nitp  = (const int*)d_in[1];
  const float* table = (const float*)d_in[2];
  const float* nw1   = (const float*)d_in[3];
  const float* nb1   = (const float*)d_in[4];
  const float* nw2   = (const float*)d_in[5];
  const float* nb2   = (const float*)d_in[6];
  const float* rw    = (const float*)d_in[7];
  const float* rb    = (const float*)d_in[8];
  const float* ww1   = (const float*)d_in[9];
  const float* wb1   = (const float*)d_in[10];
  const float* ww2   = (const float*)d_in[11];
  const float* wb2   = (const float*)d_in[12];
  const float* tw1   = (const float*)d_in[13];
  const float* tb1   = (const float*)d_in[14];
  const float* tw2   = (const float*)d_in[15];
  const float* tb2   = (const float*)d_in[16];
  const float* voidv = (const float*)d_in[17];
  const float* cw    = (const float*)d_in[18];
  const float* cb    = (const float*)d_in[19];
  const float* sw1   = (const float*)d_in[20];
  const float* sb1   = (const float*)d_in[21];
  const float* sw2   = (const float*)d_in[22];
  const float* sb2   = (const float*)d_in[23];
  float* out = (float*)d_out;
  char* ws = (char*)d_ws;

  const size_t TBL_BYTES = (size_t)50257*256*2;   // 25,731,584
  const size_t WF_BYTES  = (size_t)344064*8*2;    //  5,505,024
  const size_t EMB_BYTES = (size_t)4096*256*2;    //  2,097,152
  bool big = ws_size >= TBL_BYTES + WF_BYTES + EMB_BYTES;

  u16 *tbl16, *wfrag, *emb;
  if (big){ tbl16=(u16*)ws; wfrag=(u16*)(ws+TBL_BYTES); emb=(u16*)(ws+TBL_BYTES+WF_BYTES); }
  else    { tbl16=nullptr;  wfrag=(u16*)ws;             emb=(u16*)(ws+WF_BYTES); }

  k_pack<<<1344, 256, 0, stream>>>(nw1,nw2,rw,ww1,ww2,tw1,tw2,cw,sw1,wfrag);
  if (big){
    k_convert_table<<<(3216448+255)/256, 256, 0, stream>>>(table, tbl16, 3216448);
    k_embed<u16><<<NB, 256, 0, stream>>>(x, tbl16, emb);
  } else {
    k_embed<float><<<NB, 256, 0, stream>>>(x, table, emb);
  }
  k_main<<<256, 1024, 0, stream>>>(wfrag, emb, nb1, nb2, rb, wb1, wb2, tb1, tb2,
                                   voidv, cb, sb1, sb2, sw2, nitp, out);
}

// Round 6
// 328.159 us; speedup vs baseline: 2.8093x; 2.8093x over previous
//
#include <hip/hip_runtime.h>
#include <hip/hip_bf16.h>

#define DIM 256
#define SEQ 256
#define NB 4096
#define OUT_STRIDE 3073

typedef float f32x4 __attribute__((ext_vector_type(4)));
typedef __bf16 bf16x8 __attribute__((ext_vector_type(8)));
typedef unsigned short u16;
typedef unsigned int u32;

__device__ __forceinline__ float bf2f(u16 h){ return __uint_as_float(((u32)h)<<16); }
__device__ __forceinline__ u16 f2bf(float f){
  u32 u = __float_as_uint(f);
  return (u16)((u + 0x7FFFu + ((u>>16)&1u)) >> 16);
}
__device__ __forceinline__ float gelu_f(float x){
  float u = 0.7978845608028654f*(x + 0.044715f*x*x*x);
  float e = __expf(2.0f*u);
  float t = 1.0f - 2.0f/(e+1.0f);
  return 0.5f*x*(1.0f+t);
}
// soft barrier: sync LDS only; leave global loads/stores in flight (T4)
__device__ __forceinline__ void soft_bar(){
  asm volatile("s_waitcnt lgkmcnt(0)" ::: "memory");
  __builtin_amdgcn_s_barrier();
  asm volatile("" ::: "memory");
}

__device__ const int d_nsrc[10] = {0,1,2,1,2,2,3,2,3,3};
__device__ const int d_srcs[10][3] = {{0,0,0},{0,0,0},{0,1,0},{1,0,0},{2,3,0},
                                      {2,4,0},{1,3,5},{4,5,0},{5,6,7},{6,7,8}};

// ---------------- table f32 -> bf16 ----------------
__global__ void k_convert_table(const float* __restrict__ src, u16* __restrict__ dst, int n4){
  int i = blockIdx.x*blockDim.x + threadIdx.x;
  if (i >= n4) return;
  float4 v = ((const float4*)src)[i];
  ushort4 o; o.x=f2bf(v.x); o.y=f2bf(v.y); o.z=f2bf(v.z); o.w=f2bf(v.w);
  ((ushort4*)dst)[i] = o;
}

// ---------------- weight pack into MFMA B-fragment layout ----------------
__global__ void k_pack(const float* __restrict__ nw1, const float* __restrict__ nw2,
                       const float* __restrict__ rw,  const float* __restrict__ ww1,
                       const float* __restrict__ ww2, const float* __restrict__ tw1,
                       const float* __restrict__ tw2, const float* __restrict__ cw,
                       const float* __restrict__ sw1, u16* __restrict__ dst){
  int g = blockIdx.x*blockDim.x + threadIdx.x;
  if (g >= 344064) return;
  const float* base; int gpm, K, N, segStart;
  if      (g < 81920) { base=nw1; gpm=8192; K=256; N=256; segStart=0; }
  else if (g < 163840){ base=nw2; gpm=8192; K=256; N=256; segStart=81920; }
  else if (g < 245760){ base=rw;  gpm=8192; K=256; N=256; segStart=163840; }
  else if (g < 278528){ base=ww1; gpm=8192; K=256; N=256; segStart=245760; }
  else if (g < 311296){ base=ww2; gpm=8192; K=256; N=256; segStart=278528; }
  else if (g < 315392){ base=tw1; gpm=4096; K=256; N=128; segStart=311296; }
  else if (g < 319488){ base=tw2; gpm=4096; K=128; N=256; segStart=315392; }
  else if (g < 327680){ base=cw;  gpm=8192; K=256; N=256; segStart=319488; }
  else                { base=sw1; gpm=16384;K=256; N=512; segStart=327680; }
  int gs = g - segStart;
  int mat = gs / gpm, gl = gs % gpm;
  int lane = gl & 63, g2 = gl >> 6;
  int Nt = N >> 4;
  int t = g2 % Nt, kk = g2 / Nt;
  int col = t*16 + (lane & 15);
  int k0  = kk*32 + (lane >> 4)*8;
  const float* m = base + (size_t)mat*K*N;
  u16* o = dst + (size_t)g*8;
  (void)K;
  #pragma unroll
  for (int j=0;j<8;j++) o[j] = f2bf(m[(size_t)(k0+j)*N + col]);
}

// ---------------- embedding gather + mean ----------------
template<typename T>
__global__ void k_embed(const int* __restrict__ x, const T* __restrict__ table, u16* __restrict__ emb){
  __shared__ float red[4][256];
  int b = blockIdx.x;
  int tid = threadIdx.x, w = tid>>6, lane = tid&63;
  const int* xb = x + b*SEQ;
  float a0=0.f,a1=0.f,a2=0.f,a3=0.f;
  #pragma unroll 4
  for (int ii=0; ii<64; ii++){
    int idx = xb[w*64+ii];
    if constexpr (sizeof(T)==2){
      ushort4 v = *(const ushort4*)(table + (size_t)idx*DIM + lane*4);
      a0+=bf2f(v.x); a1+=bf2f(v.y); a2+=bf2f(v.z); a3+=bf2f(v.w);
    } else {
      float4 v = *(const float4*)(table + (size_t)idx*DIM + lane*4);
      a0+=v.x; a1+=v.y; a2+=v.z; a3+=v.w;
    }
  }
  red[w][lane*4+0]=a0; red[w][lane*4+1]=a1; red[w][lane*4+2]=a2; red[w][lane*4+3]=a3;
  __syncthreads();
  float s = (red[0][tid]+red[1][tid]+red[2][tid]+red[3][tid]) * (1.0f/SEQ);
  emb[(size_t)b*DIM + tid] = f2bf(s);
}

// ---------------- main fused network ----------------
__device__ __forceinline__ bf16x8 lds_readA(const u16* base, int rs, int kk, int lane){
  int row = lane & 15;
  int kbyte = kk*64 + (lane>>4)*16;
  return *(const bf16x8*)((const char*)base + row*rs + (kbyte ^ ((row&7)<<4)));
}

template<int KS>
__device__ __forceinline__ void loadB(bf16x8* dst, const bf16x8* __restrict__ w,
                                      int idx0, int nt, int lane){
  #pragma unroll
  for (int kk=0;kk<KS;kk++) dst[kk] = w[((size_t)(kk*nt+idx0))*64 + lane];
}
template<int KS>
__device__ __forceinline__ void mfmaK(const u16* A, int rs, const bf16x8* b, f32x4& acc, int lane){
  #pragma unroll
  for (int kk=0;kk<KS;kk++){
    bf16x8 a = lds_readA(A, rs, kk, lane);
    acc = __builtin_amdgcn_mfma_f32_16x16x32_bf16(a, b[kk], acc, 0, 0, 0);
  }
}

__device__ __forceinline__ f32x4 acc_make(float bv){
  f32x4 t = {bv,bv,bv,bv};
  return t;
}

template<bool GELU>
__device__ __forceinline__ void epi1(f32x4 acc, u16* dst, int rs, int colbase, int lane,
                                     const float* __restrict__ addcol){
  int col = colbase + (lane&15);
  float add = addcol ? addcol[col] : 0.0f;
  #pragma unroll
  for (int r=0;r<4;r++){
    int row = (lane>>4)*4 + r;
    float v = acc[r];
    if (GELU) v = gelu_f(v);
    v += add;
    *(u16*)((char*)dst + row*rs + ((col*2) ^ ((row&7)<<4))) = f2bf(v);
  }
}

// 16 waves: wave w handles row w; 4 chunks of 64 contiguous floats
__device__ __forceinline__ void out_write(const u16* buf, int rs, float* __restrict__ out,
                                          size_t rowBase, int colBase, int wave, int lane){
  int r = wave;
  int sw = (r&7)<<4;
  #pragma unroll
  for (int cc=0; cc<4; cc++){
    int c = cc*64 + lane;
    float v = bf2f(*(const u16*)((const char*)buf + r*rs + ((c*2)^sw)));
    out[(rowBase + r)*OUT_STRIDE + colBase + c] = v;
  }
}

// Node step as a MACRO: CUR/OTH bind to named arrays at compile time.
// No pointers, no lambdas -> arrays stay in VGPRs (rule #20).
// Entry: CUR = W1_i, bn1 = nb1[i].  Exit: OTH = next stage-A weights.
#define NODE_STEP(i, CUR, OTH, lastFlag) do {                                   \
    const int ns = d_nsrc[(i)];                                                 \
    loadB<8>(OTH, wf + 81920 + (size_t)(i)*8192, wave, 16, lane);               \
    float c1_ = bn1;                                                            \
    bn1 = nb2[(i)*DIM + bcol];                                                  \
    float rbv_ = (ns>0) ? rb[(i)*DIM + bcol] : 0.f;                             \
    f32x4 accA_ = acc_make(c1_);                                                \
    mfmaK<8>(&states[(i)][0][0], 512, CUR, accA_, lane);                        \
    epi1<true>(accA_, &abuf[0][0], 1024, wave*16, lane, nullptr);               \
    if (ns > 0){                                                                \
      int r_ = wave, sw_ = (r_&7)<<4;                                           \
      int off_ = ((lane*8) ^ sw_);                                              \
      const char* s0_ = (const char*)states[d_srcs[(i)][0]] + r_*512;           \
      const char* s1_ = (ns>1) ? ((const char*)states[d_srcs[(i)][1]] + r_*512) : nullptr; \
      const char* s2_ = (ns>2) ? ((const char*)states[d_srcs[(i)][2]] + r_*512) : nullptr; \
      uint2 v0_ = *(const uint2*)(s0_+off_);                                    \
      uint2 v1_, v2_; v1_.x=v1_.y=0u; v2_.x=v2_.y=0u;                           \
      if (s1_) v1_ = *(const uint2*)(s1_+off_);                                 \
      if (s2_) v2_ = *(const uint2*)(s2_+off_);                                 \
      float ax_ = __uint_as_float(v0_.x<<16) + __uint_as_float(v1_.x<<16) + __uint_as_float(v2_.x<<16); \
      float bx_ = __uint_as_float(v0_.x&0xffff0000u) + __uint_as_float(v1_.x&0xffff0000u) + __uint_as_float(v2_.x&0xffff0000u); \
      float ay_ = __uint_as_float(v0_.y<<16) + __uint_as_float(v1_.y<<16) + __uint_as_float(v2_.y<<16); \
      float by_ = __uint_as_float(v0_.y&0xffff0000u) + __uint_as_float(v1_.y&0xffff0000u) + __uint_as_float(v2_.y&0xffff0000u); \
      uint2 o_; o_.x = (u32)f2bf(ax_) | ((u32)f2bf(bx_)<<16);                   \
      o_.y = (u32)f2bf(ay_) | ((u32)f2bf(by_)<<16);                             \
      *(uint2*)((char*)abuf + r_*1024 + 512 + off_) = o_;                       \
    }                                                                           \
    soft_bar();                                                                 \
    if (ns > 0) loadB<8>(CUR, wf + 163840 + (size_t)(i)*8192, wave, 16, lane);  \
    f32x4 accB_ = acc_make(bn1 + rbv_);                                         \
    mfmaK<8>(&abuf[0][0], 1024, OTH, accB_, lane);                              \
    { const bf16x8* nW_ = ((i)<9) ? (wf + (size_t)((i)+1)*8192)                 \
                                  : (!(lastFlag) ? wf : (wf + 245760));         \
      loadB<8>(OTH, nW_, wave, 16, lane);                                       \
      bn1 = ((i)<9) ? nb1[((i)+1)*DIM + bcol] : (!(lastFlag) ? nb1[bcol] : wb1[bcol]); } \
    if (ns > 0)                                                                 \
      mfmaK<8>((const u16*)((const char*)&abuf[0][0] + 512), 1024, CUR, accB_, lane); \
    epi1<false>(accB_, &states[(i)][0][0], 512, wave*16, lane, nullptr);        \
    soft_bar();                                                                 \
    if (lastFlag)                                                               \
      out_write(&states[(i)][0][0], 512, out, (size_t)blk*16, (i)*256, wave, lane); \
  } while(0)

__global__ __launch_bounds__(1024) __attribute__((amdgpu_waves_per_eu(4)))
void k_main(
  const u16* __restrict__ wfrag, const u16* __restrict__ emb,
  const float* __restrict__ nb1, const float* __restrict__ nb2, const float* __restrict__ rb,
  const float* __restrict__ wb1, const float* __restrict__ wb2,
  const float* __restrict__ tb1, const float* __restrict__ tb2,
  const float* __restrict__ voidv, const float* __restrict__ cb,
  const float* __restrict__ sb1, const float* __restrict__ sb2, const float* __restrict__ sw2,
  const int* __restrict__ niter_p, float* __restrict__ out)
{
  __shared__ u16 states[10][16][256];   // XOR-swizzled, rs=512B
  __shared__ u16 abuf[16][512];         // rs=1024B: [:,0:256]=h1/hidden/created, [:,256:512]=inc
  __shared__ u16 cbuf[16][256];         // rs=512B : cur / contracted+void
  __shared__ u16 hbuf[16][512];         // rs=1024B: shek hidden
  __shared__ float red[16][65];

  const int tid = threadIdx.x, wave = tid>>6, lane = tid&63;
  const int blk = blockIdx.x;
  const int niter = *niter_p;
  const bf16x8* wf = (const bf16x8*)wfrag;
  const int bcol = wave*16 + (lane&15);

  // load embedded -> all 10 states (swizzled). 1024 threads: 4 bf16 (8B) each.
  {
    int r = tid >> 6, c0 = (tid & 63) * 4;
    uint2 v = *(const uint2*)(emb + ((size_t)(blk*16 + r))*DIM + c0);
    int sw = (r&7)<<4;
    #pragma unroll
    for (int st=0; st<10; st++){
      char* bp = (char*)states[st];
      *(uint2*)(bp + r*512 + ((c0*2) ^ sw)) = v;
    }
  }

  // strict 2-buffer weight pipeline; roles alternate per node via macro expansion
  bf16x8 b1[8], b2[8];
  float bn1;
  loadB<8>(b1, (niter>0) ? wf : (wf + 245760), wave, 16, lane);
  bn1 = (niter>0) ? nb1[bcol] : wb1[bcol];
  soft_bar();

  for (int it=0; it<niter; it++){
    bool last = (it == niter-1);
    #pragma unroll 1
    for (int i=0; i<10; i+=2){
      NODE_STEP(i,   b1, b2, last);
      NODE_STEP(i+1, b2, b1, last);
    }
  }
  if (niter == 0){
    #pragma unroll
    for (int st=0; st<10; st++)
      out_write(&states[st][0][0], 512, out, (size_t)blk*16, st*256, wave, lane);
  }

  // ---- worlds (entry: b1 = world_w1[0]) ----
  for (int w=0; w<4; w++){
    loadB<8>(b2, wf + 278528 + (size_t)w*8192, wave, 16, lane);   // ww2[w]
    float c1 = bn1;
    bn1 = wb2[w*DIM + bcol];
    f32x4 a1 = acc_make(c1);
    mfmaK<8>((w==0) ? &states[9][0][0] : &cbuf[0][0], 512, b1, a1, lane);
    epi1<true>(a1, &abuf[0][0], 1024, wave*16, lane, nullptr);
    soft_bar();
    f32x4 a2 = acc_make(bn1);
    mfmaK<8>(&abuf[0][0], 1024, b2, a2, lane);
    if (w < 3){
      loadB<8>(b1, wf + 245760 + (size_t)(w+1)*8192, wave, 16, lane);
      bn1 = wb1[(w+1)*DIM + bcol];
    } else {
      loadB<8>(b1, wf + 311296, wave, 8, lane);   // tz1 (NT=8); waves>=8 read junk (unused)
      bn1 = tb1[bcol & 127];
    }
    epi1<false>(a2, &cbuf[0][0], 512, wave*16, lane, nullptr);
    soft_bar();
  }
  out_write(&cbuf[0][0], 512, out, (size_t)blk*16, 2560, wave, lane);   // cur

  // ---- tz1: hidden = gelu(cur @ tz_w1 + tb1), N=128 (waves 0-7); prefetch tz2 -> b2 ----
  loadB<4>(b2, wf + 315392, wave, 16, lane);   // tz2 (KS=4)
  {
    float c1 = bn1;
    bn1 = tb2[bcol];
    if (wave < 8){
      f32x4 a = acc_make(c1);
      mfmaK<8>(&cbuf[0][0], 512, b1, a, lane);
      epi1<true>(a, &abuf[0][0], 1024, wave*16, lane, nullptr);
    }
  }
  soft_bar();
  // ---- tz2: ctv = (hidden @ tz_w2 + tb2) + void -> cbuf; prefetch cre -> b1 ----
  loadB<8>(b1, wf + 319488, wave, 16, lane);
  {
    float c1 = bn1;
    bn1 = cb[bcol];
    f32x4 a = acc_make(c1);
    mfmaK<4>(&abuf[0][0], 1024, b2, a, lane);
    epi1<false>(a, &cbuf[0][0], 512, wave*16, lane, voidv);
  }
  soft_bar();
  // ---- cre: created = ctv @ cre_w + cre_b -> abuf; prefetch shek halves -> b2, b1 ----
  loadB<8>(b2, wf + 327680, wave*2, 32, lane);
  float bnS0, bnS1;
  {
    float c1 = bn1;
    bnS0 = sb1[wave*32 + (lane&15)];
    bnS1 = sb1[wave*32 + 16 + (lane&15)];
    f32x4 a = acc_make(c1);
    mfmaK<8>(&cbuf[0][0], 512, b1, a, lane);
    loadB<8>(b1, wf + 327680, wave*2+1, 32, lane);   // shek half1 (cre weights consumed)
    epi1<false>(a, &abuf[0][0], 1024, wave*16, lane, nullptr);
  }
  soft_bar();
  // ---- shek1: h = gelu(created @ shek_w1 + sb1), N=512 -> hbuf ----
  {
    f32x4 a0 = acc_make(bnS0);
    f32x4 a1 = acc_make(bnS1);
    mfmaK<8>(&abuf[0][0], 1024, b2, a0, lane);
    mfmaK<8>(&abuf[0][0], 1024, b1, a1, lane);
    epi1<true>(a0, &hbuf[0][0], 1024, (wave*2+0)*16, lane, nullptr);
    epi1<true>(a1, &hbuf[0][0], 1024, (wave*2+1)*16, lane, nullptr);
  }
  soft_bar();
  // ---- shek2: sigmoid(h @ sw2 + sb2) -> out[:,3072] ----
  {
    int r = tid>>6, p = tid&63;
    int sw = (r&7)<<4;
    float partial = 0.f;
    #pragma unroll
    for (int j=0;j<8;j++){
      int k = p*8+j;
      partial += bf2f(*(const u16*)((const char*)hbuf + r*1024 + ((k*2)^sw))) * sw2[k];
    }
    red[r][p] = partial;
    soft_bar();
    if (tid < 16){
      float s = sb2[0];
      #pragma unroll
      for (int p2=0;p2<64;p2++) s += red[tid][p2];
      out[((size_t)(blk*16+tid))*OUT_STRIDE + 3072] = 1.f/(1.f+__expf(-s));
    }
  }
  // created -> out[:,2816:3072]  (states already written during last iteration)
  out_write(&abuf[0][0], 1024, out, (size_t)blk*16, 2816, wave, lane);
}

extern "C" void kernel_launch(void* const* d_in, const int* in_sizes, int n_in,
                              void* d_out, int out_size, void* d_ws, size_t ws_size,
                              hipStream_t stream){
  const int*   x     = (const int*)d_in[0];
  const int*   nitp  = (const int*)d_in[1];
  const float* table = (const float*)d_in[2];
  const float* nw1   = (const float*)d_in[3];
  const float* nb1   = (const float*)d_in[4];
  const float* nw2   = (const float*)d_in[5];
  const float* nb2   = (const float*)d_in[6];
  const float* rw    = (const float*)d_in[7];
  const float* rb    = (const float*)d_in[8];
  const float* ww1   = (const float*)d_in[9];
  const float* wb1   = (const float*)d_in[10];
  const float* ww2   = (const float*)d_in[11];
  const float* wb2   = (const float*)d_in[12];
  const float* tw1   = (const float*)d_in[13];
  const float* tb1   = (const float*)d_in[14];
  const float* tw2   = (const float*)d_in[15];
  const float* tb2   = (const float*)d_in[16];
  const float* voidv = (const float*)d_in[17];
  const float* cw    = (const float*)d_in[18];
  const float* cb    = (const float*)d_in[19];
  const float* sw1   = (const float*)d_in[20];
  const float* sb1   = (const float*)d_in[21];
  const float* sw2   = (const float*)d_in[22];
  const float* sb2   = (const float*)d_in[23];
  float* out = (float*)d_out;
  char* ws = (char*)d_ws;

  const size_t TBL_BYTES = (size_t)50257*256*2;   // 25,731,584
  const size_t WF_BYTES  = (size_t)344064*8*2;    //  5,505,024
  const size_t EMB_BYTES = (size_t)4096*256*2;    //  2,097,152
  bool big = ws_size >= TBL_BYTES + WF_BYTES + EMB_BYTES;

  u16 *tbl16, *wfrag, *emb;
  if (big){ tbl16=(u16*)ws; wfrag=(u16*)(ws+TBL_BYTES); emb=(u16*)(ws+TBL_BYTES+WF_BYTES); }
  else    { tbl16=nullptr;  wfrag=(u16*)ws;             emb=(u16*)(ws+WF_BYTES); }

  k_pack<<<1344, 256, 0, stream>>>(nw1,nw2,rw,ww1,ww2,tw1,tw2,cw,sw1,wfrag);
  if (big){
    k_convert_table<<<(3216448+255)/256, 256, 0, stream>>>(table, tbl16, 3216448);
    k_embed<u16><<<NB, 256, 0, stream>>>(x, tbl16, emb);
  } else {
    k_embed<float><<<NB, 256, 0, stream>>>(x, table, emb);
  }
  k_main<<<256, 1024, 0, stream>>>(wfrag, emb, nb1, nb2, rb, wb1, wb2, tb1, tb2,
                                   voidv, cb, sb1, sb2, sw2, nitp, out);
}